// Round 3
// baseline (179.828 us; speedup 1.0000x reference)
//
#include <hip/hip_runtime.h>
#include <hip/hip_bf16.h>

typedef __bf16 bf16;
typedef __bf16 bf16x4 __attribute__((ext_vector_type(4)));
typedef __bf16 bf16x8 __attribute__((ext_vector_type(8)));
typedef float  f32x16 __attribute__((ext_vector_type(16)));

#define S_  1024
#define D_  64
#define BQ  128          // 4 waves x 32 queries  (round 3: halved for occupancy)
#define BK  64
#define KT  (S_/BK)      // 16
#define QT  (S_/BQ)      // 8
#define LD  72           // bf16 stride: 144B rows, 16B-aligned

#define ZERO16 {0.f,0.f,0.f,0.f,0.f,0.f,0.f,0.f,0.f,0.f,0.f,0.f,0.f,0.f,0.f,0.f}

// S^T = K.Q^T ; O^T = V^T.P^T  with 32x32x16 MFMA, n=32 queries per wave.
// A/B: m|n=lane&31, k=(lane>>5)*8+j.  C/D: col=lane&31, row=(reg&3)+8*(reg>>2)+4*(lane>>5).
//
// KEY-PERMUTATION TRICK: softmax+PV contract over keys, so any key permutation
// applied consistently to (S rows, V^T cols) is legal. Store V key kk at LDS
// column rho(kk), rho = swap bits 2<->3 of key index. PV B-frags are then the
// lane's OWN exp'd QK output registers: no cross-lane exchange at all.
//
// ROUND 3: kernel is memory-concurrency/latency bound (all pipes <30% busy,
// hbm 1.45 TB/s = Little's law at 8 waves/CU). Rounds 1-2 showed barrier
// surgery regresses (and lambda-pointer prefetch regs spilled to scratch:
// WRITE_SIZE 33->72MB). Fix concurrency STRUCTURALLY: BQ 256->128 (wave owns
// 32 queries = one MFMA n-tile), grid 512->1024 blocks = 4 blocks/CU,
// 4 waves/SIMD (LDS 4x36.9KB=147.5 <= 160KB; VGPR halves on o/qf).
// Plain __syncthreads(), single-deep inline prefetch: the known-good pipeline.
__global__ __launch_bounds__(256, 4)
void fa_fwd(const float* __restrict__ Q, const float* __restrict__ K,
            const float* __restrict__ V, const int* __restrict__ mask,
            float* __restrict__ O)
{
    __shared__ bf16 ks[2][BK][LD];   // double-buffered K tile [key][d]
    __shared__ bf16 vt[2][D_][LD];   // double-buffered V^T tile [d][rho(key)]

    const int tid  = threadIdx.x;
    const int lane = tid & 63;
    const int w    = tid >> 6;
    const int l32  = lane & 31;
    const int hi   = lane >> 5;

    // XCD swizzle: 8 q-tiles of bh group on one XCD (bid%8 round-robin)
    const int bid   = blockIdx.x;
    const int xcd   = bid & 7;
    const int rnd   = bid >> 3;                 // 0..127
    const int qtile = rnd & 7;                  // 0..7
    const int bh    = ((rnd >> 3) << 3) | xcd;  // 0..127
    const int b     = bh >> 4;                  // H=16
    const size_t base = (size_t)bh * (S_ * D_);
    const int qW = qtile * BQ + w * 32;         // this wave's 32 queries

    const float qscale = (mask[b] != 0) ? 0.0f : 0.1803368801111204f; // log2e/8

    // ---- Q B-fragment (one n-tile): B[k=d][n=q] ----
    bf16x8 qf[4];
    {
        const float* qp = Q + base + (size_t)(qW + l32) * D_ + hi * 8;
        #pragma unroll
        for (int kc = 0; kc < 4; ++kc) {
            float4 a = *(const float4*)(qp + kc * 16);
            float4 c = *(const float4*)(qp + kc * 16 + 4);
            bf16x8 f;
            f[0] = (bf16)(a.x * qscale); f[1] = (bf16)(a.y * qscale);
            f[2] = (bf16)(a.z * qscale); f[3] = (bf16)(a.w * qscale);
            f[4] = (bf16)(c.x * qscale); f[5] = (bf16)(c.y * qscale);
            f[6] = (bf16)(c.z * qscale); f[7] = (bf16)(c.w * qscale);
            qf[kc] = f;
        }
    }

    f32x16 o[2];                     // [d-tile]
    o[0] = (f32x16)ZERO16;
    o[1] = (f32x16)ZERO16;
    float lsum = 0.f;

    const int vkq = (tid >> 2) & 15;    // V transpose: 4-key group (natural)
    const int vkp = (vkq & 12) | ((vkq & 1) << 1) | ((vkq >> 1) & 1); // rho on group
    const int vc4 = (tid & 3) + 4 * w;  // d-chunk
    const float4* gk = (const float4*)(K + base);
    const float4* gv = (const float4*)(V + base);

    // prologue: prefetch tile 0
    float4 kr[4], vr[4];
    #pragma unroll
    for (int it = 0; it < 4; ++it) kr[it] = gk[it * 256 + tid];
    #pragma unroll
    for (int r = 0; r < 4; ++r)    vr[r]  = gv[(vkq * 4 + r) * 16 + vc4];

    // exp of one 32-row S-tile; fA = chunk (2mt), fB = chunk (2mt+1), own regs only
    auto mkpf = [&](const f32x16& sv, bf16x8& fA, bf16x8& fB, float& ls) {
        bf16x8 a, c;
        #pragma unroll
        for (int i = 0; i < 8; ++i) {
            float e0 = __builtin_amdgcn_exp2f(sv[i]);
            float e1 = __builtin_amdgcn_exp2f(sv[8 + i]);
            ls += e0 + e1;
            a[i] = (bf16)e0;
            c[i] = (bf16)e1;
        }
        fA = a; fB = c;
    };

    for (int kt = 0; kt < KT; ++kt) {
        bf16 (*ksb)[LD] = ks[kt & 1];
        bf16 (*vtb)[LD] = vt[kt & 1];

        // ---- stage K tile from regs (natural key rows) ----
        #pragma unroll
        for (int it = 0; it < 4; ++it) {
            int i = it * 256 + tid;
            int row = i >> 4, c4 = i & 15;
            bf16x4 hk = {(bf16)kr[it].x, (bf16)kr[it].y, (bf16)kr[it].z, (bf16)kr[it].w};
            *(bf16x4*)&ksb[row][c4 * 4] = hk;
        }
        // ---- stage V^T from regs at rho-permuted columns ----
        {
            bf16x4 t0 = {(bf16)vr[0].x, (bf16)vr[1].x, (bf16)vr[2].x, (bf16)vr[3].x};
            bf16x4 t1 = {(bf16)vr[0].y, (bf16)vr[1].y, (bf16)vr[2].y, (bf16)vr[3].y};
            bf16x4 t2 = {(bf16)vr[0].z, (bf16)vr[1].z, (bf16)vr[2].z, (bf16)vr[3].z};
            bf16x4 t3 = {(bf16)vr[0].w, (bf16)vr[1].w, (bf16)vr[2].w, (bf16)vr[3].w};
            *(bf16x4*)&vtb[vc4 * 4 + 0][vkp * 4] = t0;
            *(bf16x4*)&vtb[vc4 * 4 + 1][vkp * 4] = t1;
            *(bf16x4*)&vtb[vc4 * 4 + 2][vkp * 4] = t2;
            *(bf16x4*)&vtb[vc4 * 4 + 3][vkp * 4] = t3;
        }
        // ---- prefetch next tile (latency under this tile's compute) ----
        {
            int ktn = (kt + 1 < KT) ? (kt + 1) : kt;
            #pragma unroll
            for (int it = 0; it < 4; ++it) kr[it] = gk[ktn * 1024 + it * 256 + tid];
            #pragma unroll
            for (int r = 0; r < 4; ++r)    vr[r]  = gv[ktn * 1024 + (vkq * 4 + r) * 16 + vc4];
        }
        __syncthreads();   // single barrier per tile (safe with double buffer)

        // ---- S^T = K.Q^T : 2 m-tiles (keys) x 1 n-tile (32 queries) ----
        f32x16 s0 = ZERO16, s1 = ZERO16;
        #pragma unroll
        for (int kc = 0; kc < 4; ++kc) {
            bf16x8 k0 = *(const bf16x8*)&ksb[l32][kc * 16 + hi * 8];
            bf16x8 k1 = *(const bf16x8*)&ksb[32 + l32][kc * 16 + hi * 8];
            s0 = __builtin_amdgcn_mfma_f32_32x32x16_bf16(k0, qf[kc], s0, 0, 0, 0);
            s1 = __builtin_amdgcn_mfma_f32_32x32x16_bf16(k1, qf[kc], s1, 0, 0, 0);
        }

        // ---- exp -> PV B-frags, all in-lane (key-permutation trick) ----
        bf16x8 pf[4];                    // [kc]
        mkpf(s0, pf[0], pf[1], lsum);
        mkpf(s1, pf[2], pf[3], lsum);

        // ---- O^T += V^T.P^T ----
        #pragma unroll
        for (int kc = 0; kc < 4; ++kc) {
            bf16x8 v0 = *(const bf16x8*)&vtb[l32][kc * 16 + hi * 8];
            bf16x8 v1 = *(const bf16x8*)&vtb[32 + l32][kc * 16 + hi * 8];
            o[0] = __builtin_amdgcn_mfma_f32_32x32x16_bf16(v0, pf[kc], o[0], 0, 0, 0);
            o[1] = __builtin_amdgcn_mfma_f32_32x32x16_bf16(v1, pf[kc], o[1], 0, 0, 0);
        }
    }

    // ---- epilogue: lane holds half the keys' sum; one cross-half add ----
    {
        float lv = lsum + __shfl_xor(lsum, 32);
        float inv = 1.0f / lv;
        float* op = O + base + (size_t)(qW + l32) * D_ + hi * 4;
        #pragma unroll
        for (int g = 0; g < 4; ++g) {
            float4 a = { o[0][g * 4 + 0] * inv, o[0][g * 4 + 1] * inv,
                         o[0][g * 4 + 2] * inv, o[0][g * 4 + 3] * inv };
            *(float4*)(op + g * 8) = a;           // d = 4hi + 8g + r
            float4 c = { o[1][g * 4 + 0] * inv, o[1][g * 4 + 1] * inv,
                         o[1][g * 4 + 2] * inv, o[1][g * 4 + 3] * inv };
            *(float4*)(op + 32 + g * 8) = c;      // d = 32 + 4hi + 8g + r
        }
    }
}

extern "C" void kernel_launch(void* const* d_in, const int* in_sizes, int n_in,
                              void* d_out, int out_size, void* d_ws, size_t ws_size,
                              hipStream_t stream)
{
    const float* Q    = (const float*)d_in[0];
    const float* K    = (const float*)d_in[1];
    const float* V    = (const float*)d_in[2];
    const int*   mask = (const int*)d_in[3];
    float*       O    = (float*)d_out;

    dim3 grid(8 * 16 * QT);   // 1024 blocks = 4 per CU
    fa_fwd<<<grid, 256, 0, stream>>>(Q, K, V, mask, O);
}

// Round 4
// 136.684 us; speedup vs baseline: 1.3156x; 1.3156x over previous
//
#include <hip/hip_runtime.h>
#include <hip/hip_bf16.h>

typedef __bf16 bf16;
typedef __bf16 bf16x4 __attribute__((ext_vector_type(4)));
typedef __bf16 bf16x8 __attribute__((ext_vector_type(8)));
typedef float  f32x16 __attribute__((ext_vector_type(16)));

#define S_  1024
#define D_  64
#define BQ  256          // 4 waves x 64 queries (R0 structure - best known)
#define BK  64
#define KT  (S_/BK)      // 16
#define QT  (S_/BQ)      // 4
#define LD  72           // bf16 stride: 144B rows, 16B-aligned

#define ZERO16 {0.f,0.f,0.f,0.f,0.f,0.f,0.f,0.f,0.f,0.f,0.f,0.f,0.f,0.f,0.f,0.f}

// S^T = K.Q^T ; O^T = V^T.P^T  with 32x32x16 MFMA, n=64 queries per wave.
// A/B: m|n=lane&31, k=(lane>>5)*8+j.  C/D: col=lane&31, row=(reg&3)+8*(reg>>2)+4*(lane>>5).
//
// KEY-PERMUTATION TRICK: softmax+PV contract over keys, so any key permutation
// applied consistently to (S rows, V^T cols) is legal. Store V key kk at LDS
// column rho(kk), rho = swap bits 2<->3. PV B-frags are then the lane's OWN
// exp'd QK output registers: no cross-lane exchange at all.
//
// ROUND 4 (algorithmic): masked batches have uniform softmax -> O = mean_k V.
// Run them on a cheap mean path (V read only; no K/Q/MFMA). Balanced static
// schedule derived from mask inside the kernel: heavy items (unmasked bh x
// qtile) take the LOWEST bids -> dispatcher spreads them one-per-CU first;
// light items (masked bh mean) next; remaining blocks exit. Heavy path is
// byte-identical to the best-known R0 kernel (57.7us). Worst-case (most
// batches unmasked) degrades to R0 behavior: bounded at neutral.
__global__ __launch_bounds__(256, 2)
void fa_fwd(const float* __restrict__ Q, const float* __restrict__ K,
            const float* __restrict__ V, const int* __restrict__ mask,
            float* __restrict__ O)
{
    __shared__ bf16 ks[2][BK][LD];   // double-buffered K tile [key][d]
    __shared__ bf16 vt[2][D_][LD];   // double-buffered V^T tile [d][rho(key)]

    const int tid  = threadIdx.x;
    const int lane = tid & 63;
    const int w    = tid >> 6;
    const int l32  = lane & 31;
    const int hi   = lane >> 5;
    const int bid  = blockIdx.x;

    // ---- schedule from mask (uniform scalar work) ----
    int m0 = mask[0], m1 = mask[1], m2 = mask[2], m3 = mask[3];
    int m4 = mask[4], m5 = mask[5], m6 = mask[6], m7 = mask[7];
    int um[8] = { m0 == 0, m1 == 0, m2 == 0, m3 == 0,
                  m4 == 0, m5 == 0, m6 == 0, m7 == 0 };
    int U = 0;
    #pragma unroll
    for (int i = 0; i < 8; ++i) U += um[i];
    const int nHeavy = 64 * U;            // (unmasked bh) x 4 qtiles
    const int nLight = 16 * (8 - U);      // one per masked bh

    int bh, qtile;
    bool light;
    if (bid < nHeavy) {
        // XCD-aware: xcd = bid&7 keeps a bh group's tiles on one XCD
        const int xcd = bid & 7;
        const int r   = bid >> 3;             // 0..8U-1
        qtile = r & 3;
        const int g   = r >> 2;               // 0..2U-1
        const int bh_rank = (g << 3) | xcd;   // 0..16U-1 over unmasked bh list
        const int ub   = bh_rank >> 4;        // rank among unmasked batches
        const int head = bh_rank & 15;
        int b = 0, cnt = 0;
        #pragma unroll
        for (int i = 0; i < 8; ++i) { if (um[i]) { if (cnt == ub) b = i; ++cnt; } }
        bh = b * 16 + head;
        light = false;
    } else if (bid < nHeavy + nLight) {
        const int lid    = bid - nHeavy;      // 0..16M-1
        const int m_rank = lid >> 4;          // rank among masked batches
        const int head   = lid & 15;
        int b = 0, cnt = 0;
        #pragma unroll
        for (int i = 0; i < 8; ++i) { if (!um[i]) { if (cnt == m_rank) b = i; ++cnt; } }
        bh = b * 16 + head;
        qtile = 0;
        light = true;
    } else {
        return;                               // surplus block
    }

    const size_t base = (size_t)bh * (S_ * D_);

    if (light) {
        // ---- masked bh: O[q,:] = mean_k V[k,:] for all q (exact) ----
        const float4* gvl = (const float4*)(V + base);
        float4*       gol = (float4*)(O + base);
        const int d4 = tid & 15;              // float4 column
        const int rg = tid >> 4;              // 16 row groups of 64 rows
        float4 acc = {0.f, 0.f, 0.f, 0.f};
        #pragma unroll 4
        for (int r = 0; r < 64; ++r) {
            float4 v = gvl[(rg * 64 + r) * 16 + d4];
            acc.x += v.x; acc.y += v.y; acc.z += v.z; acc.w += v.w;
        }
        float4 (*red)[16] = (float4(*)[16])&ks[0][0][0];   // 4KB LDS alias
        red[rg][d4] = acc;
        __syncthreads();
        if (tid < 16) {
            float4 s = red[0][tid];
            #pragma unroll
            for (int g = 1; g < 16; ++g) {
                float4 t = red[g][tid];
                s.x += t.x; s.y += t.y; s.z += t.z; s.w += t.w;
            }
            const float sc = 1.0f / 1024.0f;
            s.x *= sc; s.y *= sc; s.z *= sc; s.w *= sc;
            red[0][tid] = s;
        }
        __syncthreads();
        float4 mv = red[0][d4];
        #pragma unroll 4
        for (int k = 0; k < 64; ++k)
            gol[(rg + 16 * k) * 16 + d4] = mv;   // 16 rows x 256B per iter
        return;
    }

    // ================= heavy path: identical to R0 (best known) =============
    const int qW = qtile * BQ + w * 64;
    const float qscale = 0.1803368801111204f;    // log2e/8 (always unmasked here)

    // ---- Q B-fragments for 2 n-tiles: B[k=d][n=q] ----
    bf16x8 qf[2][4];
    #pragma unroll
    for (int nt = 0; nt < 2; ++nt) {
        const float* qp = Q + base + (size_t)(qW + nt * 32 + l32) * D_ + hi * 8;
        #pragma unroll
        for (int kc = 0; kc < 4; ++kc) {
            float4 a = *(const float4*)(qp + kc * 16);
            float4 c = *(const float4*)(qp + kc * 16 + 4);
            bf16x8 f;
            f[0] = (bf16)(a.x * qscale); f[1] = (bf16)(a.y * qscale);
            f[2] = (bf16)(a.z * qscale); f[3] = (bf16)(a.w * qscale);
            f[4] = (bf16)(c.x * qscale); f[5] = (bf16)(c.y * qscale);
            f[6] = (bf16)(c.z * qscale); f[7] = (bf16)(c.w * qscale);
            qf[nt][kc] = f;
        }
    }

    f32x16 o[2][2];                  // [d-tile][n-tile]
    #pragma unroll
    for (int dm = 0; dm < 2; ++dm)
        #pragma unroll
        for (int nt = 0; nt < 2; ++nt) o[dm][nt] = (f32x16)ZERO16;
    float lsum[2] = {0.f, 0.f};

    const int vkq = (tid >> 2) & 15;    // V transpose: 4-key group (natural)
    const int vkp = (vkq & 12) | ((vkq & 1) << 1) | ((vkq >> 1) & 1); // rho on group
    const int vc4 = (tid & 3) + 4 * w;  // d-chunk
    const float4* gk = (const float4*)(K + base);
    const float4* gv = (const float4*)(V + base);

    // prologue: prefetch tile 0
    float4 kr[4], vr[4];
    #pragma unroll
    for (int it = 0; it < 4; ++it) kr[it] = gk[it * 256 + tid];
    #pragma unroll
    for (int r = 0; r < 4; ++r)    vr[r]  = gv[(vkq * 4 + r) * 16 + vc4];

    // exp of one 32-row S-tile; fA = chunk (2mt), fB = chunk (2mt+1), own regs only
    auto mkpf = [&](const f32x16& sv, bf16x8& fA, bf16x8& fB, float& ls) {
        bf16x8 a, c;
        #pragma unroll
        for (int i = 0; i < 8; ++i) {
            float e0 = __builtin_amdgcn_exp2f(sv[i]);
            float e1 = __builtin_amdgcn_exp2f(sv[8 + i]);
            ls += e0 + e1;
            a[i] = (bf16)e0;
            c[i] = (bf16)e1;
        }
        fA = a; fB = c;
    };

    for (int kt = 0; kt < KT; ++kt) {
        bf16 (*ksb)[LD] = ks[kt & 1];
        bf16 (*vtb)[LD] = vt[kt & 1];

        // ---- stage K tile from regs (natural key rows) ----
        #pragma unroll
        for (int it = 0; it < 4; ++it) {
            int i = it * 256 + tid;
            int row = i >> 4, c4 = i & 15;
            bf16x4 hk = {(bf16)kr[it].x, (bf16)kr[it].y, (bf16)kr[it].z, (bf16)kr[it].w};
            *(bf16x4*)&ksb[row][c4 * 4] = hk;
        }
        // ---- stage V^T from regs at rho-permuted columns ----
        {
            bf16x4 t0 = {(bf16)vr[0].x, (bf16)vr[1].x, (bf16)vr[2].x, (bf16)vr[3].x};
            bf16x4 t1 = {(bf16)vr[0].y, (bf16)vr[1].y, (bf16)vr[2].y, (bf16)vr[3].y};
            bf16x4 t2 = {(bf16)vr[0].z, (bf16)vr[1].z, (bf16)vr[2].z, (bf16)vr[3].z};
            bf16x4 t3 = {(bf16)vr[0].w, (bf16)vr[1].w, (bf16)vr[2].w, (bf16)vr[3].w};
            *(bf16x4*)&vtb[vc4 * 4 + 0][vkp * 4] = t0;
            *(bf16x4*)&vtb[vc4 * 4 + 1][vkp * 4] = t1;
            *(bf16x4*)&vtb[vc4 * 4 + 2][vkp * 4] = t2;
            *(bf16x4*)&vtb[vc4 * 4 + 3][vkp * 4] = t3;
        }
        // ---- prefetch next tile (latency under this tile's compute) ----
        {
            int ktn = (kt + 1 < KT) ? (kt + 1) : kt;
            #pragma unroll
            for (int it = 0; it < 4; ++it) kr[it] = gk[ktn * 1024 + it * 256 + tid];
            #pragma unroll
            for (int r = 0; r < 4; ++r)    vr[r]  = gv[ktn * 1024 + (vkq * 4 + r) * 16 + vc4];
        }
        __syncthreads();   // single barrier per tile (safe with double buffer)

        // ---- S^T = K.Q^T : 2 m-tiles (keys) x 2 n-tiles (queries) ----
        f32x16 s00 = ZERO16, s01 = ZERO16, s10 = ZERO16, s11 = ZERO16;
        #pragma unroll
        for (int kc = 0; kc < 4; ++kc) {
            bf16x8 k0 = *(const bf16x8*)&ksb[l32][kc * 16 + hi * 8];
            bf16x8 k1 = *(const bf16x8*)&ksb[32 + l32][kc * 16 + hi * 8];
            s00 = __builtin_amdgcn_mfma_f32_32x32x16_bf16(k0, qf[0][kc], s00, 0, 0, 0);
            s01 = __builtin_amdgcn_mfma_f32_32x32x16_bf16(k0, qf[1][kc], s01, 0, 0, 0);
            s10 = __builtin_amdgcn_mfma_f32_32x32x16_bf16(k1, qf[0][kc], s10, 0, 0, 0);
            s11 = __builtin_amdgcn_mfma_f32_32x32x16_bf16(k1, qf[1][kc], s11, 0, 0, 0);
        }

        // ---- exp -> PV B-frags, all in-lane (key-permutation trick) ----
        bf16x8 pf[4][2];                 // [kc][nt]
        mkpf(s00, pf[0][0], pf[1][0], lsum[0]);
        mkpf(s01, pf[0][1], pf[1][1], lsum[1]);
        mkpf(s10, pf[2][0], pf[3][0], lsum[0]);
        mkpf(s11, pf[2][1], pf[3][1], lsum[1]);

        // ---- O^T += V^T.P^T ----
        #pragma unroll
        for (int kc = 0; kc < 4; ++kc) {
            bf16x8 v0 = *(const bf16x8*)&vtb[l32][kc * 16 + hi * 8];
            bf16x8 v1 = *(const bf16x8*)&vtb[32 + l32][kc * 16 + hi * 8];
            o[0][0] = __builtin_amdgcn_mfma_f32_32x32x16_bf16(v0, pf[kc][0], o[0][0], 0, 0, 0);
            o[0][1] = __builtin_amdgcn_mfma_f32_32x32x16_bf16(v0, pf[kc][1], o[0][1], 0, 0, 0);
            o[1][0] = __builtin_amdgcn_mfma_f32_32x32x16_bf16(v1, pf[kc][0], o[1][0], 0, 0, 0);
            o[1][1] = __builtin_amdgcn_mfma_f32_32x32x16_bf16(v1, pf[kc][1], o[1][1], 0, 0, 0);
        }
    }

    // ---- epilogue: lane holds half the keys' sum; one cross-half add ----
    #pragma unroll
    for (int nt = 0; nt < 2; ++nt) {
        float lv = lsum[nt] + __shfl_xor(lsum[nt], 32);
        float inv = 1.0f / lv;
        float* op = O + base + (size_t)(qW + nt * 32 + l32) * D_ + hi * 4;
        #pragma unroll
        for (int g = 0; g < 4; ++g) {
            float4 a = { o[0][nt][g * 4 + 0] * inv, o[0][nt][g * 4 + 1] * inv,
                         o[0][nt][g * 4 + 2] * inv, o[0][nt][g * 4 + 3] * inv };
            *(float4*)(op + g * 8) = a;           // d = 4hi + 8g + r
            float4 c = { o[1][nt][g * 4 + 0] * inv, o[1][nt][g * 4 + 1] * inv,
                         o[1][nt][g * 4 + 2] * inv, o[1][nt][g * 4 + 3] * inv };
            *(float4*)(op + 32 + g * 8) = c;      // d = 32 + 4hi + 8g + r
        }
    }
}

extern "C" void kernel_launch(void* const* d_in, const int* in_sizes, int n_in,
                              void* d_out, int out_size, void* d_ws, size_t ws_size,
                              hipStream_t stream)
{
    const float* Q    = (const float*)d_in[0];
    const float* K    = (const float*)d_in[1];
    const float* V    = (const float*)d_in[2];
    const int*   mask = (const int*)d_in[3];
    float*       O    = (float*)d_out;

    // grid covers worst case: all-unmasked = 512 heavy blocks (surplus exits)
    dim3 grid(8 * 16 * QT);
    fa_fwd<<<grid, 256, 0, stream>>>(Q, K, V, mask, O);
}